// Round 4
// baseline (389.517 us; speedup 1.0000x reference)
//
#include <hip/hip_runtime.h>
#include <cmath>

static constexpr int B = 8;
static constexpr int C = 768;
static constexpr int L = 2048;
static constexpr int BC = B * C;        // 6144
static constexpr int NROWS = 2 * BC;    // 12288

__device__ __forceinline__ unsigned rotl32(unsigned x, unsigned r) {
    return (x << r) | (x >> (32u - r));
}

// JAX threefry2x32 (matches jax/_src/prng.py lowering exactly)
__device__ __forceinline__ void threefry2x32(unsigned k0, unsigned k1,
                                             unsigned& x0, unsigned& x1) {
    const unsigned ks2 = k0 ^ k1 ^ 0x1BD11BDAu;
    const unsigned r0[4] = {13u, 15u, 26u, 6u};
    const unsigned r1[4] = {17u, 29u, 16u, 24u};
    x0 += k0; x1 += k1;
#pragma unroll
    for (int j = 0; j < 4; ++j) { x0 += x1; x1 = rotl32(x1, r0[j]); x1 ^= x0; }
    x0 += k1; x1 += ks2 + 1u;
#pragma unroll
    for (int j = 0; j < 4; ++j) { x0 += x1; x1 = rotl32(x1, r1[j]); x1 ^= x0; }
    x0 += ks2; x1 += k0 + 2u;
#pragma unroll
    for (int j = 0; j < 4; ++j) { x0 += x1; x1 = rotl32(x1, r0[j]); x1 ^= x0; }
    x0 += k0; x1 += k1 + 3u;
#pragma unroll
    for (int j = 0; j < 4; ++j) { x0 += x1; x1 = rotl32(x1, r1[j]); x1 ^= x0; }
    x0 += k1; x1 += ks2 + 4u;
#pragma unroll
    for (int j = 0; j < 4; ++j) { x0 += x1; x1 = rotl32(x1, r0[j]); x1 ^= x0; }
    x0 += ks2; x1 += k0 + 5u;
}

// K1: per-row mean over L. One wave per row; 2 inputs * 6144 rows = 12288 waves.
// HBM-bound: 100.7 MB stream, floor ~16 us.
__global__ __launch_bounds__(256) void mean_rows(const float* __restrict__ xcin,
                                                 const float* __restrict__ ycin,
                                                 float* __restrict__ m) {
    const int wid  = (blockIdx.x * 256 + threadIdx.x) >> 6;
    const int lane = threadIdx.x & 63;
    const float* src = (wid < BC) ? xcin : ycin;
    const int row = (wid < BC) ? wid : wid - BC;
    const float4* p = reinterpret_cast<const float4*>(src + (size_t)row * L);
    float s = 0.f;
#pragma unroll
    for (int k = 0; k < L / (4 * 64); ++k) {      // 8 iterations, coalesced float4
        float4 v = p[k * 64 + lane];
        s += (v.x + v.y) + (v.z + v.w);
    }
#pragma unroll
    for (int off = 32; off > 0; off >>= 1) s += __shfl_down(s, off, 64);
    if (lane == 0) m[wid] = s * (1.0f / (float)L);
}

// K2 (fused stage 2+3): one block per (s,b); pooled lives in LDS.
// Thread t streams Wk/Wo/Wt row t from L2 (rows are contiguous 3 KB, float4).
// Then RNG + combine epilogue per output. 16 blocks x 768 threads.
__global__ __launch_bounds__(768) void fused_heads(
        const float* __restrict__ m,
        const float* __restrict__ Wk, const float* __restrict__ bk,
        const float* __restrict__ Wo, const float* __restrict__ bo,
        const float* __restrict__ Wt, const float* __restrict__ bt,
        const float* __restrict__ xog0, const float* __restrict__ xog1,
        const float* __restrict__ yog0, const float* __restrict__ yog1,
        float* __restrict__ out) {
    __shared__ __align__(16) float m_s[C];
    __shared__ __align__(16) float pooled_s[C];

    const int sb = blockIdx.x;              // 0..15
    const int t  = threadIdx.x;             // 0..767 = output channel o
    const int s  = sb >> 3;                 // 0 = xout, 1 = yout
    const int b  = sb & 7;

    m_s[t] = m[sb * C + t];
    __syncthreads();

    // Phase A: pooled[t] = bk[t] + sum_c Wk[t,c] * m_s[c]
    {
        const float4* wr = reinterpret_cast<const float4*>(Wk + (size_t)t * C);
        const float4* mv = reinterpret_cast<const float4*>(m_s);
        float a0 = 0.f, a1 = 0.f, a2 = 0.f, a3 = 0.f;
#pragma unroll 8
        for (int i = 0; i < C / 4; ++i) {   // 192 float4 loads
            float4 w = wr[i], v = mv[i];
            a0 += w.x * v.x; a1 += w.y * v.y; a2 += w.z * v.z; a3 += w.w * v.w;
        }
        pooled_s[t] = (a0 + a1) + (a2 + a3) + bk[t];
    }
    __syncthreads();

    // Phase B: two heads off pooled_s
    float ao, at;
    {
        const float4* wo = reinterpret_cast<const float4*>(Wo + (size_t)t * C);
        const float4* wt = reinterpret_cast<const float4*>(Wt + (size_t)t * C);
        const float4* pv = reinterpret_cast<const float4*>(pooled_s);
        float o0 = 0.f, o1 = 0.f, o2 = 0.f, o3 = 0.f;
        float t0 = 0.f, t1 = 0.f, t2 = 0.f, t3 = 0.f;
#pragma unroll 4
        for (int i = 0; i < C / 4; ++i) {
            float4 p = pv[i];
            float4 a = wo[i];
            float4 c = wt[i];
            o0 += a.x * p.x; o1 += a.y * p.y; o2 += a.z * p.z; o3 += a.w * p.w;
            t0 += c.x * p.x; t1 += c.y * p.y; t2 += c.z * p.z; t3 += c.w * p.w;
        }
        ao = (o0 + o1) + (o2 + o3) + bo[t];
        at = (t0 + t1) + (t2 + t3) + bt[t];
    }

    const float* og0 = s ? yog0 : xog0;
    const float* og1 = s ? yog1 : xog1;
    const float mo = fmaxf(ao, 0.f) + og0[b * C + t];
    const float lv = fmaxf(at, 0.f) + og1[b * C + t];

    // --- JAX RNG (threefry, partitionable scheme, default in jax>=0.4.36) ---
    // ek1, ek2 = split(key(42)): foldlike -> ek_i = threefry((0,42), (0,i))
    unsigned e10 = 0u, e11 = 0u; threefry2x32(0u, 42u, e10, e11);  // ek1
    unsigned e20 = 0u, e21 = 1u; threefry2x32(0u, 42u, e20, e21);  // ek2
    const unsigned kk0 = s ? e20 : e10;
    const unsigned kk1 = s ? e21 : e11;
    // random_bits(ek, 32, (8,768)): bits_i = hi ^ lo of threefry(ek, (0,i))
    unsigned h = 0u, l = (unsigned)(b * C + t);
    threefry2x32(kk0, kk1, h, l);
    const unsigned bits = h ^ l;
    // uniform in [lo,1): f in [0,1), u = max(lo, f*(hi-lo)+lo); (hi-lo) rounds to 2.0f
    const unsigned fb = (bits >> 9) | 0x3F800000u;
    const float f  = __uint_as_float(fb) - 1.0f;
    const float mn = -0.99999994f;                 // nextafter(-1,0)
    const float u  = fmaxf(mn, f * 2.0f + mn);
    const float nrm = 1.4142135623730951f * erfinvf(u);   // sqrt(2)*erfinv
    const float eps = 0.1f * nrm;

    out[sb * C + t] = eps * expf(0.5f * lv) + mo;
}

extern "C" void kernel_launch(void* const* d_in, const int* in_sizes, int n_in,
                              void* d_out, int out_size, void* d_ws, size_t ws_size,
                              hipStream_t stream) {
    const float* xcin = (const float*)d_in[0];
    const float* ycin = (const float*)d_in[1];
    const float* xog0 = (const float*)d_in[2];
    const float* xog1 = (const float*)d_in[3];
    const float* yog0 = (const float*)d_in[4];
    const float* yog1 = (const float*)d_in[5];
    // d_in[6] = Wq, d_in[7] = bq: mathematically cancel (softmax rows sum to 1,
    // mean-pool over the attention output axis washes the attention out) -> unused.
    const float* Wk = (const float*)d_in[8];
    const float* bk = (const float*)d_in[9];
    const float* Wo = (const float*)d_in[10];
    const float* bo = (const float*)d_in[11];
    const float* Wt = (const float*)d_in[12];
    const float* bt = (const float*)d_in[13];
    float* out = (float*)d_out;

    float* m = (float*)d_ws;           // 12288 floats

    hipLaunchKernelGGL(mean_rows, dim3(NROWS * 64 / 256), dim3(256), 0, stream,
                       xcin, ycin, m);
    hipLaunchKernelGGL(fused_heads, dim3(2 * B), dim3(C), 0, stream,
                       m, Wk, bk, Wo, bo, Wt, bt, xog0, xog1, yog0, yog1, out);
}

// Round 5
// 159.011 us; speedup vs baseline: 2.4496x; 2.4496x over previous
//
#include <hip/hip_runtime.h>
#include <cmath>

static constexpr int B = 8;
static constexpr int C = 768;
static constexpr int L = 2048;
static constexpr int BC = B * C;        // 6144
static constexpr int NROWS = 2 * BC;    // 12288

__device__ __forceinline__ unsigned rotl32(unsigned x, unsigned r) {
    return (x << r) | (x >> (32u - r));
}

// JAX threefry2x32 (matches jax/_src/prng.py lowering exactly)
__device__ __forceinline__ void threefry2x32(unsigned k0, unsigned k1,
                                             unsigned& x0, unsigned& x1) {
    const unsigned ks2 = k0 ^ k1 ^ 0x1BD11BDAu;
    const unsigned r0[4] = {13u, 15u, 26u, 6u};
    const unsigned r1[4] = {17u, 29u, 16u, 24u};
    x0 += k0; x1 += k1;
#pragma unroll
    for (int j = 0; j < 4; ++j) { x0 += x1; x1 = rotl32(x1, r0[j]); x1 ^= x0; }
    x0 += k1; x1 += ks2 + 1u;
#pragma unroll
    for (int j = 0; j < 4; ++j) { x0 += x1; x1 = rotl32(x1, r1[j]); x1 ^= x0; }
    x0 += ks2; x1 += k0 + 2u;
#pragma unroll
    for (int j = 0; j < 4; ++j) { x0 += x1; x1 = rotl32(x1, r0[j]); x1 ^= x0; }
    x0 += k0; x1 += k1 + 3u;
#pragma unroll
    for (int j = 0; j < 4; ++j) { x0 += x1; x1 = rotl32(x1, r1[j]); x1 ^= x0; }
    x0 += k1; x1 += ks2 + 4u;
#pragma unroll
    for (int j = 0; j < 4; ++j) { x0 += x1; x1 = rotl32(x1, r0[j]); x1 ^= x0; }
    x0 += ks2; x1 += k0 + 5u;
}

// K1: per-row mean over L. One wave per row; 2 inputs * 6144 rows = 12288 waves.
// HBM-bound: 100.7 MB stream, floor ~16 us at 6.3 TB/s.
__global__ __launch_bounds__(256) void mean_rows(const float* __restrict__ xcin,
                                                 const float* __restrict__ ycin,
                                                 float* __restrict__ m) {
    const int wid  = (blockIdx.x * 256 + threadIdx.x) >> 6;
    const int lane = threadIdx.x & 63;
    const float* src = (wid < BC) ? xcin : ycin;
    const int row = (wid < BC) ? wid : wid - BC;
    const float4* p = reinterpret_cast<const float4*>(src + (size_t)row * L);
    float s = 0.f;
#pragma unroll
    for (int k = 0; k < L / (4 * 64); ++k) {      // 8 iterations, coalesced float4
        float4 v = p[k * 64 + lane];
        s += (v.x + v.y) + (v.z + v.w);
    }
#pragma unroll
    for (int off = 32; off > 0; off >>= 1) s += __shfl_down(s, off, 64);
    if (lane == 0) m[wid] = s * (1.0f / (float)L);
}

// K2: pooled[s,b,o] = sum_c Wk[o,c]*m[s,b,c] + bk[o]. One wave per output.
// 12288 waves spread weight traffic across all 256 CUs (lesson from round 4:
// 16-block fusion concentrated L2 traffic on 16 CUs -> 252 us; this form ~4 us).
__global__ __launch_bounds__(256) void pooled_k(const float* __restrict__ m,
                                                const float* __restrict__ Wk,
                                                const float* __restrict__ bk,
                                                float* __restrict__ pooled) {
    const int wid  = (blockIdx.x * 256 + threadIdx.x) >> 6;
    const int lane = threadIdx.x & 63;
    const int o  = wid % C;
    const int sb = wid / C;                 // 0..15 = (s,b)
    const float* mv = m + sb * C;
    const float* wr = Wk + (size_t)o * C;
    float acc = 0.f;
#pragma unroll
    for (int k = 0; k < C / 64; ++k)        // 12 iterations, coalesced
        acc += wr[k * 64 + lane] * mv[k * 64 + lane];
#pragma unroll
    for (int off = 32; off > 0; off >>= 1) acc += __shfl_down(acc, off, 64);
    if (lane == 0) pooled[wid] = acc + bk[o];
}

// K3: mean/logvar heads + threefry eps + final combine. One wave per output.
__global__ __launch_bounds__(256) void out_k(const float* __restrict__ pooled,
                                             const float* __restrict__ Wo,
                                             const float* __restrict__ bo,
                                             const float* __restrict__ Wt,
                                             const float* __restrict__ bt,
                                             const float* __restrict__ xog0,
                                             const float* __restrict__ xog1,
                                             const float* __restrict__ yog0,
                                             const float* __restrict__ yog1,
                                             float* __restrict__ out) {
    const int wid  = (blockIdx.x * 256 + threadIdx.x) >> 6;
    const int lane = threadIdx.x & 63;
    const int o  = wid % C;
    const int sb = wid / C;
    const int s  = sb >> 3;                 // 0 = xout, 1 = yout
    const int b  = sb & 7;
    const float* pv = pooled + sb * C;
    const float* wo = Wo + (size_t)o * C;
    const float* wt = Wt + (size_t)o * C;
    float ao = 0.f, at = 0.f;
#pragma unroll
    for (int k = 0; k < C / 64; ++k) {
        float p = pv[k * 64 + lane];
        ao += wo[k * 64 + lane] * p;
        at += wt[k * 64 + lane] * p;
    }
#pragma unroll
    for (int off = 32; off > 0; off >>= 1) {
        ao += __shfl_down(ao, off, 64);
        at += __shfl_down(at, off, 64);
    }
    if (lane == 0) {
        const float* og0 = s ? yog0 : xog0;
        const float* og1 = s ? yog1 : xog1;
        const float mo = fmaxf(ao + bo[o], 0.f) + og0[b * C + o];
        const float lv = fmaxf(at + bt[o], 0.f) + og1[b * C + o];

        // --- JAX RNG (threefry, partitionable scheme, default in jax>=0.4.36) ---
        // ek1, ek2 = split(key(42)): foldlike -> ek_i = threefry((0,42), (0,i))
        // (compile-time constants; compiler folds these two calls)
        unsigned e10 = 0u, e11 = 0u; threefry2x32(0u, 42u, e10, e11);  // ek1
        unsigned e20 = 0u, e21 = 1u; threefry2x32(0u, 42u, e20, e21);  // ek2
        const unsigned kk0 = s ? e20 : e10;
        const unsigned kk1 = s ? e21 : e11;
        // random_bits(ek, 32, (8,768)): bits_i = hi ^ lo of threefry(ek, (0,i))
        unsigned h = 0u, l = (unsigned)(b * C + o);
        threefry2x32(kk0, kk1, h, l);
        const unsigned bits = h ^ l;
        // uniform in [lo,1): f in [0,1), u = max(lo, f*(hi-lo)+lo); (hi-lo) rounds to 2.0f
        const unsigned fb = (bits >> 9) | 0x3F800000u;
        const float f  = __uint_as_float(fb) - 1.0f;
        const float mn = -0.99999994f;                 // nextafter(-1,0)
        const float u  = fmaxf(mn, f * 2.0f + mn);
        const float nrm = 1.4142135623730951f * erfinvf(u);   // sqrt(2)*erfinv
        const float eps = 0.1f * nrm;

        out[wid] = eps * expf(0.5f * lv) + mo;
    }
}

extern "C" void kernel_launch(void* const* d_in, const int* in_sizes, int n_in,
                              void* d_out, int out_size, void* d_ws, size_t ws_size,
                              hipStream_t stream) {
    const float* xcin = (const float*)d_in[0];
    const float* ycin = (const float*)d_in[1];
    const float* xog0 = (const float*)d_in[2];
    const float* xog1 = (const float*)d_in[3];
    const float* yog0 = (const float*)d_in[4];
    const float* yog1 = (const float*)d_in[5];
    // d_in[6] = Wq, d_in[7] = bq: mathematically cancel (softmax rows sum to 1,
    // mean-pool over the attention output axis washes the attention out) -> unused.
    const float* Wk = (const float*)d_in[8];
    const float* bk = (const float*)d_in[9];
    const float* Wo = (const float*)d_in[10];
    const float* bo = (const float*)d_in[11];
    const float* Wt = (const float*)d_in[12];
    const float* bt = (const float*)d_in[13];
    float* out = (float*)d_out;

    float* m      = (float*)d_ws;      // 12288 floats
    float* pooled = m + NROWS;         // 12288 floats

    const dim3 blk(256);
    const dim3 grid(NROWS * 64 / 256); // 3072 blocks = 12288 waves
    hipLaunchKernelGGL(mean_rows, grid, blk, 0, stream, xcin, ycin, m);
    hipLaunchKernelGGL(pooled_k,  grid, blk, 0, stream, m, Wk, bk, pooled);
    hipLaunchKernelGGL(out_k,     grid, blk, 0, stream, pooled, Wo, bo, Wt, bt,
                       xog0, xog1, yog0, yog1, out);
}